// Round 16
// baseline (161.371 us; speedup 1.0000x reference)
//
#include <hip/hip_runtime.h>
#include <hip/hip_bf16.h>

#define BT_TOTAL 1024

typedef __bf16 bf16x8 __attribute__((ext_vector_type(8)));
typedef float  f32x4  __attribute__((ext_vector_type(4)));
typedef int    i32x4  __attribute__((ext_vector_type(4)));
typedef short  s16x4  __attribute__((ext_vector_type(4)));

__device__ inline unsigned short f2bf(float f) {
    unsigned int u = __builtin_bit_cast(unsigned int, f);
    u = (u + 0x7FFFu + ((u >> 16) & 1u)) >> 16;
    return (unsigned short)u;
}

__device__ inline bf16x8 ldsb8(const unsigned short* p) {
    i32x4 t = *(const i32x4*)p;
    return __builtin_bit_cast(bf16x8, t);
}

#define SB0() __builtin_amdgcn_sched_barrier(0)

// Counter separation (r15-proven): B on vmcnt (asm gloads), A on lgkmcnt
// (ds_reads) — the ONLY ops on each counter inside K-loops (biases/epilogues
// sit behind __syncthreads). So counted waits are exact:
//   WAITV4/2: prior B-tile retired (newest 4/2 = next tile in flight)
//   WAITL4:   A(t) retired (newest 4 = A(t+1) prefetch in flight)
// SB0 after each wait (rule-18) and after each prefetch issue (anti-sink).
#define WAITV4() do { \
    asm volatile("s_waitcnt vmcnt(4)" ::: "memory"); SB0(); } while (0)
#define WAITV2() do { \
    asm volatile("s_waitcnt vmcnt(2)" ::: "memory"); SB0(); } while (0)
#define WAITV0() do { \
    asm volatile("s_waitcnt vmcnt(0)" ::: "memory"); SB0(); } while (0)
#define WAITL4() do { \
    asm volatile("s_waitcnt lgkmcnt(4)" ::: "memory"); SB0(); } while (0)

// global -> VGPR, saddr form; asm volatile = cannot be sunk/folded (r8/r9 fix).
#define GLOAD4(d, vo, sb, IMM) \
    asm volatile("global_load_dwordx4 %0, %1, %2 offset:" IMM \
                 : "=v"(d) : "v"(vo), "s"(sb) : "memory")

// ---------------- prep: fragment-direct pack (r9/r15-verified layout) ----------------
__global__ __launch_bounds__(512) void prep_pack(
    const float* __restrict__ W1, const float* __restrict__ W2,
    const float* __restrict__ W3,
    unsigned short* __restrict__ wt1, unsigned short* __restrict__ wt2,
    unsigned short* __restrict__ wt3)
{
    int p = blockIdx.x * 512 + threadIdx.x;      // 0 .. 458751
    const float* src; unsigned short* dst; int N_, Wc;
    if (p < 65536)       { src = W1; dst = wt1; N_ = 512; Wc = 64; }
    else if (p < 327680) { p -= 65536;  src = W2; dst = wt2; N_ = 512; Wc = 64; }
    else                 { p -= 327680; src = W3; dst = wt3; N_ = 256; Wc = 32; }
    int k = p / N_, n = p % N_;
    int t = k >> 5, kk = k & 31, l4 = kk >> 3, j = kk & 7;
    int wv = n / Wc, nc = n % Wc, nt = nc >> 4, l16 = nc & 15;
    int off = t * (N_ * 32) + wv * (Wc * 32) + nt * 512 + (l4 * 16 + l16) * 8 + j;
    dst[off] = f2bf(src[(size_t)k * N_ + n]);
}

// ======================= K1: fused MLP — B in regs, A via LDS, both 1-step prefetched =======================
// LDS: H [64][520]us = 66560 -> 2 blocks/CU. obs staged into H cols 0..127 for L1.
// EMB overlay [64][264]us @0 post-L3.
#define K1_LDS 66560

__global__ __launch_bounds__(512, 4) void mlp_kernel(
    const float* __restrict__ obs,
    const unsigned short* __restrict__ C1, const float* __restrict__ b1,
    const unsigned short* __restrict__ C2, const float* __restrict__ b2,
    const unsigned short* __restrict__ C3, const float* __restrict__ b3,
    unsigned short* __restrict__ embOut)   // per bt: RM [64][256] then CM [256][64]
{
    extern __shared__ __align__(16) char smem[];
    unsigned short* H   = (unsigned short*)smem;   // [64][520]
    unsigned short* EMB = (unsigned short*)smem;   // [64][264] (post-L3 overlay)

    const int bt = blockIdx.x, tid = threadIdx.x;
    const int lane = tid & 63, wv = tid >> 6;   // 8 waves
    const int l16 = lane & 15, l4 = lane >> 4;

    const int voff  = wv * 4096 + lane * 16;    // L1/L2 slice
    const int voff3 = wv * 2048 + lane * 16;    // L3 slice

    i32x4 breg[2][4];

    // ---- prologue: issue B1(0); stage obs -> H cols 0..127 (bf16) ----
    GLOAD4(breg[0][0], voff, C1, "0");
    GLOAD4(breg[0][1], voff, C1, "1024");
    GLOAD4(breg[0][2], voff, C1, "2048");
    GLOAD4(breg[0][3], voff, C1, "3072");
    {
        const f32x4* src = (const f32x4*)(obs + (size_t)bt * 8192);
#pragma unroll
        for (int i = 0; i < 4; ++i) {
            int idx = tid + i * 512;            // 0..2047
            f32x4 v = src[idx];
            int row = idx >> 5, c4 = idx & 31;
            s16x4 s;
            s[0] = (short)f2bf(v.x); s[1] = (short)f2bf(v.y);
            s[2] = (short)f2bf(v.z); s[3] = (short)f2bf(v.w);
            *(s16x4*)(H + row * 520 + c4 * 4) = s;
        }
    }
    __syncthreads();   // drains obs writes + B1(0); H cols 0..127 = obs bf16

    // ---- L1: 4 steps; A from H cols 0..127, cross-step prefetched ----
    // mfma(b, a, acc) computes C^T: acc[i] -> (col n = l4*4+i, row m = l16)
    f32x4 acc1[4][4] = {};
    {
        bf16x8 afr[4], afn[4];
#pragma unroll
        for (int mt = 0; mt < 4; ++mt)
            afr[mt] = ldsb8(H + (mt * 16 + l16) * 520 + l4 * 8);   // A(0)
        SB0();
#pragma unroll
        for (int t = 0; t < 4; ++t) {
            if (t < 3) {
                const unsigned short* sb = C1 + (size_t)(t + 1) * 16384;
                GLOAD4(breg[(t + 1) & 1][0], voff, sb, "0");
                GLOAD4(breg[(t + 1) & 1][1], voff, sb, "1024");
                GLOAD4(breg[(t + 1) & 1][2], voff, sb, "2048");
                GLOAD4(breg[(t + 1) & 1][3], voff, sb, "3072");
            }
            int tn = (t + 1) & 3;
#pragma unroll
            for (int mt = 0; mt < 4; ++mt)
                afn[mt] = ldsb8(H + (mt * 16 + l16) * 520 + tn * 32 + l4 * 8);
            SB0();                               // pin afn issue before waits
            if (t < 3) WAITV4(); else WAITV0();
            WAITL4();                            // retires A(t); A(t+1) in flight
#pragma unroll
            for (int nt = 0; nt < 4; ++nt) {
                bf16x8 bq = __builtin_bit_cast(bf16x8, breg[t & 1][nt]);
#pragma unroll
                for (int mt = 0; mt < 4; ++mt)
                    acc1[mt][nt] = __builtin_amdgcn_mfma_f32_16x16x32_bf16(bq, afr[mt], acc1[mt][nt], 0, 0, 0);
            }
#pragma unroll
            for (int mt = 0; mt < 4; ++mt) afr[mt] = afn[mt];
        }
    }
    __syncthreads();   // drains stray A-prefetch; ALL waves' obs reads done
    // epilogue: H = relu(acc1^T + b1); issue B2(0) before the publishing sync
    {
        f32x4 bv[4];
#pragma unroll
        for (int nt = 0; nt < 4; ++nt)
            bv[nt] = *(const f32x4*)(b1 + wv * 64 + nt * 16 + l4 * 4);
#pragma unroll
        for (int mt = 0; mt < 4; ++mt) {
            int row = mt * 16 + l16;
#pragma unroll
            for (int nt = 0; nt < 4; ++nt) {
                f32x4 v = acc1[mt][nt] + bv[nt];
                s16x4 s;
#pragma unroll
                for (int i = 0; i < 4; ++i) s[i] = (short)f2bf(fmaxf(v[i], 0.f));
                *(s16x4*)(H + row * 520 + wv * 64 + nt * 16 + l4 * 4) = s;
            }
        }
    }
    GLOAD4(breg[0][0], voff, C2, "0");
    GLOAD4(breg[0][1], voff, C2, "1024");
    GLOAD4(breg[0][2], voff, C2, "2048");
    GLOAD4(breg[0][3], voff, C2, "3072");
    __syncthreads();   // H1 visible; B2(0) drained

    // ---- L2: 16 steps, A+B cross-step prefetched ----
    f32x4 acc2[4][4] = {};
    {
        bf16x8 afr[4], afn[4];
#pragma unroll
        for (int mt = 0; mt < 4; ++mt)
            afr[mt] = ldsb8(H + (mt * 16 + l16) * 520 + l4 * 8);   // A(0)
        SB0();
#pragma unroll
        for (int t = 0; t < 16; ++t) {
            if (t < 15) {
                const unsigned short* sb = C2 + (size_t)(t + 1) * 16384;
                GLOAD4(breg[(t + 1) & 1][0], voff, sb, "0");
                GLOAD4(breg[(t + 1) & 1][1], voff, sb, "1024");
                GLOAD4(breg[(t + 1) & 1][2], voff, sb, "2048");
                GLOAD4(breg[(t + 1) & 1][3], voff, sb, "3072");
            }
            int tn = (t + 1) & 15;
#pragma unroll
            for (int mt = 0; mt < 4; ++mt)
                afn[mt] = ldsb8(H + (mt * 16 + l16) * 520 + tn * 32 + l4 * 8);
            SB0();
            if (t < 15) WAITV4(); else WAITV0();
            WAITL4();
#pragma unroll
            for (int nt = 0; nt < 4; ++nt) {
                bf16x8 bq = __builtin_bit_cast(bf16x8, breg[t & 1][nt]);
#pragma unroll
                for (int mt = 0; mt < 4; ++mt)
                    acc2[mt][nt] = __builtin_amdgcn_mfma_f32_16x16x32_bf16(bq, afr[mt], acc2[mt][nt], 0, 0, 0);
            }
#pragma unroll
            for (int mt = 0; mt < 4; ++mt) afr[mt] = afn[mt];
        }
    }
    __syncthreads();   // all H1 reads (incl. stray prefetch) done before overwrite
    {
        f32x4 bv[4];
#pragma unroll
        for (int nt = 0; nt < 4; ++nt)
            bv[nt] = *(const f32x4*)(b2 + wv * 64 + nt * 16 + l4 * 4);
#pragma unroll
        for (int mt = 0; mt < 4; ++mt) {
            int row = mt * 16 + l16;
#pragma unroll
            for (int nt = 0; nt < 4; ++nt) {
                f32x4 v = acc2[mt][nt] + bv[nt];
                s16x4 s;
#pragma unroll
                for (int i = 0; i < 4; ++i) s[i] = (short)f2bf(fmaxf(v[i], 0.f));
                *(s16x4*)(H + row * 520 + wv * 64 + nt * 16 + l4 * 4) = s;
            }
        }
    }
    GLOAD4(breg[0][0], voff3, C3, "0");
    GLOAD4(breg[0][1], voff3, C3, "1024");
    __syncthreads();   // H2 visible; B3(0) drained

    // ---- L3: 16 steps (K=512), N=256, A+B prefetched ----
    f32x4 acc3[4][2] = {};
    {
        bf16x8 afr[4], afn[4];
#pragma unroll
        for (int mt = 0; mt < 4; ++mt)
            afr[mt] = ldsb8(H + (mt * 16 + l16) * 520 + l4 * 8);   // A(0)
        SB0();
#pragma unroll
        for (int t = 0; t < 16; ++t) {
            if (t < 15) {
                const unsigned short* sb = C3 + (size_t)(t + 1) * 8192;
                GLOAD4(breg[(t + 1) & 1][0], voff3, sb, "0");
                GLOAD4(breg[(t + 1) & 1][1], voff3, sb, "1024");
            }
            int tn = (t + 1) & 15;
#pragma unroll
            for (int mt = 0; mt < 4; ++mt)
                afn[mt] = ldsb8(H + (mt * 16 + l16) * 520 + tn * 32 + l4 * 8);
            SB0();
            if (t < 15) WAITV2(); else WAITV0();
            WAITL4();
#pragma unroll
            for (int nt = 0; nt < 2; ++nt) {
                bf16x8 bq = __builtin_bit_cast(bf16x8, breg[t & 1][nt]);
#pragma unroll
                for (int mt = 0; mt < 4; ++mt)
                    acc3[mt][nt] = __builtin_amdgcn_mfma_f32_16x16x32_bf16(bq, afr[mt], acc3[mt][nt], 0, 0, 0);
            }
#pragma unroll
            for (int mt = 0; mt < 4; ++mt) afr[mt] = afn[mt];
        }
    }
    __syncthreads();   // all H reads done; EMB overlay writable

    // ---- emb epilogue: bf16 tile in LDS (b64 writes), then global RM + CM ----
    {
        f32x4 bv[2];
#pragma unroll
        for (int nt = 0; nt < 2; ++nt)
            bv[nt] = *(const f32x4*)(b3 + wv * 32 + nt * 16 + l4 * 4);
#pragma unroll
        for (int mt = 0; mt < 4; ++mt) {
            int row = mt * 16 + l16;
#pragma unroll
            for (int nt = 0; nt < 2; ++nt) {
                f32x4 v = acc3[mt][nt] + bv[nt];
                s16x4 s;
#pragma unroll
                for (int i = 0; i < 4; ++i) s[i] = (short)f2bf(v[i]);
                *(s16x4*)(EMB + row * 264 + wv * 32 + nt * 16 + l4 * 4) = s;
            }
        }
    }
    __syncthreads();
    {
        unsigned short* eR = embOut + (size_t)bt * 32768;
        unsigned short* eC = eR + 16384;
        // RM: [64][256] = 2048 x 16B groups (coalesced)
#pragma unroll
        for (int u = 0; u < 4; ++u) {
            int uu = tid + u * 512;                 // 0..2047
            int row = uu >> 5, c8 = (uu & 31) * 8;
            i32x4 v = *(const i32x4*)(EMB + row * 264 + c8);
            *(i32x4*)(eR + uu * 8) = v;             // eR[row*256 + c8]
        }
        // CM: lane <-> column-consecutive (2-way LDS reads, free)
#pragma unroll
        for (int u = 0; u < 4; ++u) {
            int v = tid + u * 512;                  // 0..2047
            int col = v & 255, rg = v >> 8;
            i32x4 w;
#pragma unroll
            for (int j = 0; j < 4; ++j) {
                unsigned int a = EMB[(rg * 8 + 2 * j) * 264 + col];
                unsigned int b = EMB[(rg * 8 + 2 * j + 1) * 264 + col];
                w[j] = (int)(a | (b << 16));
            }
            *(i32x4*)(eC + col * 64 + rg * 8) = w;  // eC[col*64 + rg*8]
        }
    }
}

// ======================= K2: attention (unchanged, verified) =======================
// LDS: W1A [16][72]us @0 (2304) ; TCM [256][40]us @2304 (20480) ;
//      TF [16][260]f32 @22784 (16640) ; W2A [64][40]us @39424 (5120) ;
//      MK [64]i32 @44544 (256) ; SMX/SSM @44800 (512) ; TQ [16][264]us @45312 (8448)
#define K2_LDS 53760

__global__ void attn_kernel(const int* __restrict__ amask,
                            const float* __restrict__ tq,
                            const unsigned short* __restrict__ emb,
                            float* __restrict__ outT, float* __restrict__ outC)
{
    extern __shared__ __align__(16) char smem[];
    unsigned short* W1A = (unsigned short*)smem;
    unsigned short* TCM = (unsigned short*)(smem + 2304);
    float*          TF  = (float*)(smem + 22784);
    unsigned short* W2A = (unsigned short*)(smem + 39424);
    int*            MK  = (int*)(smem + 44544);
    float*          SMX = (float*)(smem + 44800);
    float*          SSM = SMX + 64;
    unsigned short* TQ  = (unsigned short*)(smem + 45312);  // [16][264]

    const int bt = blockIdx.x, tid = threadIdx.x;
    const int lane = tid & 63, w = tid >> 6;
    const int l16 = lane & 15, l4 = lane >> 4;
    const unsigned short* eR = emb + (size_t)bt * 32768;
    const unsigned short* eC = eR + 16384;

    if (tid < 64) MK[tid] = amask[(size_t)bt * 64 + tid];
#pragma unroll
    for (int i = 0; i < 16; ++i) {
        int idx = tid + i * 256;
        int row = idx >> 8, col = idx & 255;
        TQ[row * 264 + col] = f2bf(tq[idx]);
    }
    __syncthreads();

    float sv[4]; int msk;
    {
        f32x4 acc = {};
#pragma unroll
        for (int kk = 0; kk < 8; ++kk) {
            int ko = kk*32 + l4*8;
            bf16x8 a = ldsb8(TQ + l16 * 264 + ko);
            bf16x8 b = ldsb8(eR + (w*16 + l16) * 256 + ko);
            acc = __builtin_amdgcn_mfma_f32_16x16x32_bf16(a, b, acc, 0, 0, 0);
        }
        msk = MK[w*16 + l16];
#pragma unroll
        for (int i = 0; i < 4; ++i) sv[i] = msk ? acc[i] * 0.0625f : -3.0e38f;
        float mx[4];
#pragma unroll
        for (int i = 0; i < 4; ++i) {
            float m = sv[i];
#pragma unroll
            for (int off = 1; off < 16; off <<= 1) m = fmaxf(m, __shfl_xor(m, off, 16));
            mx[i] = m;
        }
        if (l16 == 0) {
#pragma unroll
            for (int i = 0; i < 4; ++i) SMX[(l4*4 + i) * 4 + w] = mx[i];
        }
    }
    __syncthreads();
    float ev[4];
    {
#pragma unroll
        for (int i = 0; i < 4; ++i) {
            int q = l4*4 + i;
            float g = fmaxf(fmaxf(SMX[q*4+0], SMX[q*4+1]), fmaxf(SMX[q*4+2], SMX[q*4+3]));
            ev[i] = msk ? __expf(sv[i] - g) : 0.f;
            float s = ev[i];
#pragma unroll
            for (int off = 1; off < 16; off <<= 1) s += __shfl_xor(s, off, 16);
            if (l16 == 0) SSM[q*4 + w] = s;
        }
    }
    __syncthreads();
    {
#pragma unroll
        for (int i = 0; i < 4; ++i) {
            int q = l4*4 + i;
            float tot = SSM[q*4+0] + SSM[q*4+1] + SSM[q*4+2] + SSM[q*4+3];
            float w1 = ev[i] * (1.0f / fmaxf(tot, 1e-8f));
            W1A[q * 72 + w*16 + l16] = f2bf(w1);
        }
    }
    __syncthreads();

    {
        bf16x8 bW[2];
#pragma unroll
        for (int kk = 0; kk < 2; ++kk) bW[kk] = ldsb8(W1A + l16 * 72 + kk*32 + l4*8);
#pragma unroll
        for (int p = 0; p < 4; ++p) {
            int dt = w + p * 4;
            f32x4 acc = {};
#pragma unroll
            for (int kk = 0; kk < 2; ++kk) {
                bf16x8 a = ldsb8(eC + (dt*16 + l16) * 64 + kk*32 + l4*8);
                acc = __builtin_amdgcn_mfma_f32_16x16x32_bf16(a, bW[kk], acc, 0, 0, 0);
            }
#pragma unroll
            for (int i = 0; i < 4; ++i) {
                int d = dt*16 + l4*4 + i;
                TCM[d * 40 + l16]      = f2bf(acc[i]);
                TCM[d * 40 + 16 + l16] = 0;
                TF[l16 * 260 + d]      = acc[i];
            }
        }
    }
    __syncthreads();

    {
        float* oT = outT + (size_t)bt * 4096;
#pragma unroll
        for (int it = 0; it < 16; ++it) {
            int idx = tid + it * 256;
            oT[idx] = TF[(idx >> 8) * 260 + (idx & 255)];
        }
    }

    {
        f32x4 acc = {};
#pragma unroll
        for (int kk = 0; kk < 8; ++kk) {
            int ko = kk*32 + l4*8;
            bf16x8 a = ldsb8(eR + (w*16 + l16) * 256 + ko);
            const float* tp = TF + l16 * 260 + ko;
            f32x4 t0 = *(const f32x4*)tp;
            f32x4 t1 = *(const f32x4*)(tp + 4);
            bf16x8 b;
            b[0]=(__bf16)t0.x; b[1]=(__bf16)t0.y; b[2]=(__bf16)t0.z; b[3]=(__bf16)t0.w;
            b[4]=(__bf16)t1.x; b[5]=(__bf16)t1.y; b[6]=(__bf16)t1.z; b[7]=(__bf16)t1.w;
            acc = __builtin_amdgcn_mfma_f32_16x16x32_bf16(a, b, acc, 0, 0, 0);
        }
#pragma unroll
        for (int i = 0; i < 4; ++i) {
            float s = acc[i] * 0.0625f;
            float m = s;
#pragma unroll
            for (int off = 1; off < 16; off <<= 1) m = fmaxf(m, __shfl_xor(m, off, 16));
            float e = __expf(s - m);
            float su = e;
#pragma unroll
            for (int off = 1; off < 16; off <<= 1) su += __shfl_xor(su, off, 16);
            float w2 = e / su;
            int ag = w*16 + l4*4 + i;
            W2A[ag * 40 + l16]      = f2bf(w2);
            W2A[ag * 40 + 16 + l16] = 0;
        }
    }
    __syncthreads();

    {
        float* oC = outC + (size_t)bt * 16384;
        bf16x8 a = ldsb8(W2A + (w*16 + l16) * 40 + l4*8);
#pragma unroll
        for (int dt = 0; dt < 16; ++dt) {
            bf16x8 b = ldsb8(TCM + (dt*16 + l16) * 40 + l4*8);
            f32x4 acc = {};
            acc = __builtin_amdgcn_mfma_f32_16x16x32_bf16(a, b, acc, 0, 0, 0);
#pragma unroll
            for (int i = 0; i < 4; ++i) {
                int ag = w*16 + l4*4 + i;
                float m = (float)MK[ag];
                oC[ag * 256 + dt*16 + l16] = acc[i] * m;
            }
        }
    }
}

extern "C" void kernel_launch(void* const* d_in, const int* in_sizes, int n_in,
                              void* d_out, int out_size, void* d_ws, size_t ws_size,
                              hipStream_t stream) {
    (void)in_sizes; (void)n_in; (void)out_size; (void)ws_size;
    const float* obs   = (const float*)d_in[0];
    const int*   amask = (const int*)d_in[1];
    const float* W1    = (const float*)d_in[2];
    const float* b1    = (const float*)d_in[3];
    const float* W2    = (const float*)d_in[4];
    const float* b2    = (const float*)d_in[5];
    const float* W3    = (const float*)d_in[6];
    const float* b3    = (const float*)d_in[7];
    const float* tq    = (const float*)d_in[8];

    unsigned short* wt1 = (unsigned short*)d_ws;       // 65536 elems (frag-packed)
    unsigned short* wt2 = wt1 + 65536;                 // 262144 elems
    unsigned short* wt3 = wt2 + 262144;                // 131072 elems

    float* outT = (float*)d_out;
    float* outC = outT + (size_t)BT_TOTAL * 16 * 256;
    unsigned short* embWS = (unsigned short*)outC;     // emb staged in outC region

    prep_pack<<<896, 512, 0, stream>>>(W1, W2, W3, wt1, wt2, wt3);
    mlp_kernel<<<BT_TOTAL, 512, K1_LDS, stream>>>(
        obs, wt1, b1, wt2, b2, wt3, b3, embWS);
    attn_kernel<<<BT_TOTAL, 256, K2_LDS, stream>>>(
        amask, tq, embWS, outT, outC);
}

// Round 17
// 102.961 us; speedup vs baseline: 1.5673x; 1.5673x over previous
//
#include <hip/hip_runtime.h>
#include <hip/hip_bf16.h>

#define BT_TOTAL 1024

typedef __bf16 bf16x8 __attribute__((ext_vector_type(8)));
typedef float  f32x4  __attribute__((ext_vector_type(4)));
typedef int    i32x4  __attribute__((ext_vector_type(4)));
typedef short  s16x4  __attribute__((ext_vector_type(4)));

__device__ inline unsigned short f2bf(float f) {
    unsigned int u = __builtin_bit_cast(unsigned int, f);
    u = (u + 0x7FFFu + ((u >> 16) & 1u)) >> 16;
    return (unsigned short)u;
}

__device__ inline bf16x8 ldsb8(const unsigned short* p) {
    i32x4 t = *(const i32x4*)p;
    return __builtin_bit_cast(bf16x8, t);
}

#define SB0() __builtin_amdgcn_sched_barrier(0)

// Counter separation (r15-proven): B on vmcnt (asm gloads), A on lgkmcnt.
// Counted waits exact: no other vmem in K-loops (biases/epilogues behind
// __syncthreads). A-reads issued BEFORE the vm-wait so their LDS latency
// hides under it; compiler inserts the lgkmcnt before MFMA use.
#define WAITV4() do { \
    asm volatile("s_waitcnt vmcnt(4)" ::: "memory"); SB0(); } while (0)
#define WAITV2() do { \
    asm volatile("s_waitcnt vmcnt(2)" ::: "memory"); SB0(); } while (0)
#define WAITV0() do { \
    asm volatile("s_waitcnt vmcnt(0)" ::: "memory"); SB0(); } while (0)

// global -> VGPR, saddr form; asm volatile = cannot be sunk/folded (r8/r9 fix).
#define GLOAD4(d, vo, sb, IMM) \
    asm volatile("global_load_dwordx4 %0, %1, %2 offset:" IMM \
                 : "=v"(d) : "v"(vo), "s"(sb) : "memory")

// ---------------- prep: fragment-direct pack (r9/r15-verified layout) ----------------
__global__ __launch_bounds__(512) void prep_pack(
    const float* __restrict__ W1, const float* __restrict__ W2,
    const float* __restrict__ W3,
    unsigned short* __restrict__ wt1, unsigned short* __restrict__ wt2,
    unsigned short* __restrict__ wt3)
{
    int p = blockIdx.x * 512 + threadIdx.x;      // 0 .. 458751
    const float* src; unsigned short* dst; int N_, Wc;
    if (p < 65536)       { src = W1; dst = wt1; N_ = 512; Wc = 64; }
    else if (p < 327680) { p -= 65536;  src = W2; dst = wt2; N_ = 512; Wc = 64; }
    else                 { p -= 327680; src = W3; dst = wt3; N_ = 256; Wc = 32; }
    int k = p / N_, n = p % N_;
    int t = k >> 5, kk = k & 31, l4 = kk >> 3, j = kk & 7;
    int wv = n / Wc, nc = n % Wc, nt = nc >> 4, l16 = nc & 15;
    int off = t * (N_ * 32) + wv * (Wc * 32) + nt * 512 + (l4 * 16 + l16) * 8 + j;
    dst[off] = f2bf(src[(size_t)k * N_ + n]);
}

// ======================= K1: fused MLP — B in registers, A via LDS =======================
// LDS: H [64][520]us = 66560 -> 2 blocks/CU. obs staged into H cols 0..127 for L1.
// EMB overlay [64][264]us @0 post-L3.
#define K1_LDS 66560

__global__ __launch_bounds__(512, 4) void mlp_kernel(
    const float* __restrict__ obs,
    const unsigned short* __restrict__ C1, const float* __restrict__ b1,
    const unsigned short* __restrict__ C2, const float* __restrict__ b2,
    const unsigned short* __restrict__ C3, const float* __restrict__ b3,
    unsigned short* __restrict__ embOut)   // per bt: RM [64][256] then CM [256][64]
{
    extern __shared__ __align__(16) char smem[];
    unsigned short* H   = (unsigned short*)smem;   // [64][520]
    unsigned short* EMB = (unsigned short*)smem;   // [64][264] (post-L3 overlay)

    const int bt = blockIdx.x, tid = threadIdx.x;
    const int lane = tid & 63, wv = tid >> 6;   // 8 waves
    const int l16 = lane & 15, l4 = lane >> 4;

    const int voff  = wv * 4096 + lane * 16;    // L1/L2 slice
    const int voff3 = wv * 2048 + lane * 16;    // L3 slice

    i32x4 breg[2][4];

    // ---- prologue: issue B1(0); stage obs -> H cols 0..127 (bf16) ----
    GLOAD4(breg[0][0], voff, C1, "0");
    GLOAD4(breg[0][1], voff, C1, "1024");
    GLOAD4(breg[0][2], voff, C1, "2048");
    GLOAD4(breg[0][3], voff, C1, "3072");
    {
        const f32x4* src = (const f32x4*)(obs + (size_t)bt * 8192);
#pragma unroll
        for (int i = 0; i < 4; ++i) {
            int idx = tid + i * 512;            // 0..2047
            f32x4 v = src[idx];
            int row = idx >> 5, c4 = idx & 31;
            s16x4 s;
            s[0] = (short)f2bf(v.x); s[1] = (short)f2bf(v.y);
            s[2] = (short)f2bf(v.z); s[3] = (short)f2bf(v.w);
            *(s16x4*)(H + row * 520 + c4 * 4) = s;
        }
    }
    __syncthreads();   // drains obs loads + B1(0); H cols 0..127 = obs bf16

    // ---- L1: 4 steps; A from H cols 0..127 ----
    // mfma(b, a, acc) computes C^T: acc[i] -> (col n = l4*4+i, row m = l16)
    f32x4 acc1[4][4] = {};
#pragma unroll
    for (int t = 0; t < 4; ++t) {
        if (t < 3) {
            const unsigned short* sb = C1 + (size_t)(t + 1) * 16384;
            GLOAD4(breg[(t + 1) & 1][0], voff, sb, "0");
            GLOAD4(breg[(t + 1) & 1][1], voff, sb, "1024");
            GLOAD4(breg[(t + 1) & 1][2], voff, sb, "2048");
            GLOAD4(breg[(t + 1) & 1][3], voff, sb, "3072");
        }
        bf16x8 afr[4];
#pragma unroll
        for (int mt = 0; mt < 4; ++mt)   // issue A(t) BEFORE the vm-wait
            afr[mt] = ldsb8(H + (mt * 16 + l16) * 520 + t * 32 + l4 * 8);
        if (t < 3) WAITV4(); else WAITV0();
#pragma unroll
        for (int nt = 0; nt < 4; ++nt) {
            bf16x8 bq = __builtin_bit_cast(bf16x8, breg[t & 1][nt]);
#pragma unroll
            for (int mt = 0; mt < 4; ++mt)
                acc1[mt][nt] = __builtin_amdgcn_mfma_f32_16x16x32_bf16(bq, afr[mt], acc1[mt][nt], 0, 0, 0);
        }
    }
    __syncthreads();   // ALL waves' obs reads done before H overwrite
    // epilogue: H = relu(acc1^T + b1); issue B2(0) before the publishing sync
    {
        f32x4 bv[4];
#pragma unroll
        for (int nt = 0; nt < 4; ++nt)
            bv[nt] = *(const f32x4*)(b1 + wv * 64 + nt * 16 + l4 * 4);
#pragma unroll
        for (int mt = 0; mt < 4; ++mt) {
            int row = mt * 16 + l16;
#pragma unroll
            for (int nt = 0; nt < 4; ++nt) {
                f32x4 v = acc1[mt][nt] + bv[nt];
                s16x4 s;
#pragma unroll
                for (int i = 0; i < 4; ++i) s[i] = (short)f2bf(fmaxf(v[i], 0.f));
                *(s16x4*)(H + row * 520 + wv * 64 + nt * 16 + l4 * 4) = s;
            }
        }
    }
    GLOAD4(breg[0][0], voff, C2, "0");
    GLOAD4(breg[0][1], voff, C2, "1024");
    GLOAD4(breg[0][2], voff, C2, "2048");
    GLOAD4(breg[0][3], voff, C2, "3072");
    __syncthreads();   // H1 visible; B2(0) drained

    // ---- L2: 16 steps ----
    f32x4 acc2[4][4] = {};
#pragma unroll
    for (int t = 0; t < 16; ++t) {
        if (t < 15) {
            const unsigned short* sb = C2 + (size_t)(t + 1) * 16384;
            GLOAD4(breg[(t + 1) & 1][0], voff, sb, "0");
            GLOAD4(breg[(t + 1) & 1][1], voff, sb, "1024");
            GLOAD4(breg[(t + 1) & 1][2], voff, sb, "2048");
            GLOAD4(breg[(t + 1) & 1][3], voff, sb, "3072");
        }
        bf16x8 afr[4];
#pragma unroll
        for (int mt = 0; mt < 4; ++mt)   // A(t) issued before the vm-wait
            afr[mt] = ldsb8(H + (mt * 16 + l16) * 520 + t * 32 + l4 * 8);
        if (t < 15) WAITV4(); else WAITV0();
#pragma unroll
        for (int nt = 0; nt < 4; ++nt) {
            bf16x8 bq = __builtin_bit_cast(bf16x8, breg[t & 1][nt]);
#pragma unroll
            for (int mt = 0; mt < 4; ++mt)
                acc2[mt][nt] = __builtin_amdgcn_mfma_f32_16x16x32_bf16(bq, afr[mt], acc2[mt][nt], 0, 0, 0);
        }
    }
    __syncthreads();   // all H1 reads done before overwrite
    {
        f32x4 bv[4];
#pragma unroll
        for (int nt = 0; nt < 4; ++nt)
            bv[nt] = *(const f32x4*)(b2 + wv * 64 + nt * 16 + l4 * 4);
#pragma unroll
        for (int mt = 0; mt < 4; ++mt) {
            int row = mt * 16 + l16;
#pragma unroll
            for (int nt = 0; nt < 4; ++nt) {
                f32x4 v = acc2[mt][nt] + bv[nt];
                s16x4 s;
#pragma unroll
                for (int i = 0; i < 4; ++i) s[i] = (short)f2bf(fmaxf(v[i], 0.f));
                *(s16x4*)(H + row * 520 + wv * 64 + nt * 16 + l4 * 4) = s;
            }
        }
    }
    GLOAD4(breg[0][0], voff3, C3, "0");
    GLOAD4(breg[0][1], voff3, C3, "1024");
    __syncthreads();   // H2 visible; B3(0) drained

    // ---- L3: 16 steps (K=512), N=256 ----
    f32x4 acc3[4][2] = {};
#pragma unroll
    for (int t = 0; t < 16; ++t) {
        if (t < 15) {
            const unsigned short* sb = C3 + (size_t)(t + 1) * 8192;
            GLOAD4(breg[(t + 1) & 1][0], voff3, sb, "0");
            GLOAD4(breg[(t + 1) & 1][1], voff3, sb, "1024");
        }
        bf16x8 afr[4];
#pragma unroll
        for (int mt = 0; mt < 4; ++mt)   // A(t) issued before the vm-wait
            afr[mt] = ldsb8(H + (mt * 16 + l16) * 520 + t * 32 + l4 * 8);
        if (t < 15) WAITV2(); else WAITV0();
#pragma unroll
        for (int nt = 0; nt < 2; ++nt) {
            bf16x8 bq = __builtin_bit_cast(bf16x8, breg[t & 1][nt]);
#pragma unroll
            for (int mt = 0; mt < 4; ++mt)
                acc3[mt][nt] = __builtin_amdgcn_mfma_f32_16x16x32_bf16(bq, afr[mt], acc3[mt][nt], 0, 0, 0);
        }
    }
    __syncthreads();   // all H reads done; EMB overlay writable

    // ---- emb epilogue: bf16 tile in LDS (b64 writes), then global RM + CM ----
    {
        f32x4 bv[2];
#pragma unroll
        for (int nt = 0; nt < 2; ++nt)
            bv[nt] = *(const f32x4*)(b3 + wv * 32 + nt * 16 + l4 * 4);
#pragma unroll
        for (int mt = 0; mt < 4; ++mt) {
            int row = mt * 16 + l16;
#pragma unroll
            for (int nt = 0; nt < 2; ++nt) {
                f32x4 v = acc3[mt][nt] + bv[nt];
                s16x4 s;
#pragma unroll
                for (int i = 0; i < 4; ++i) s[i] = (short)f2bf(v[i]);
                *(s16x4*)(EMB + row * 264 + wv * 32 + nt * 16 + l4 * 4) = s;
            }
        }
    }
    __syncthreads();
    {
        unsigned short* eR = embOut + (size_t)bt * 32768;
        unsigned short* eC = eR + 16384;
        // RM: [64][256] = 2048 x 16B groups (coalesced)
#pragma unroll
        for (int u = 0; u < 4; ++u) {
            int uu = tid + u * 512;                 // 0..2047
            int row = uu >> 5, c8 = (uu & 31) * 8;
            i32x4 v = *(const i32x4*)(EMB + row * 264 + c8);
            *(i32x4*)(eR + uu * 8) = v;             // eR[row*256 + c8]
        }
        // CM: lane <-> column-consecutive (2-way LDS reads, free)
#pragma unroll
        for (int u = 0; u < 4; ++u) {
            int v = tid + u * 512;                  // 0..2047
            int col = v & 255, rg = v >> 8;
            i32x4 w;
#pragma unroll
            for (int j = 0; j < 4; ++j) {
                unsigned int a = EMB[(rg * 8 + 2 * j) * 264 + col];
                unsigned int b = EMB[(rg * 8 + 2 * j + 1) * 264 + col];
                w[j] = (int)(a | (b << 16));
            }
            *(i32x4*)(eC + col * 64 + rg * 8) = w;  // eC[col*64 + rg*8]
        }
    }
}

// ======================= K2: attention (unchanged, verified) =======================
// LDS: W1A [16][72]us @0 (2304) ; TCM [256][40]us @2304 (20480) ;
//      TF [16][260]f32 @22784 (16640) ; W2A [64][40]us @39424 (5120) ;
//      MK [64]i32 @44544 (256) ; SMX/SSM @44800 (512) ; TQ [16][264]us @45312 (8448)
#define K2_LDS 53760

__global__ void attn_kernel(const int* __restrict__ amask,
                            const float* __restrict__ tq,
                            const unsigned short* __restrict__ emb,
                            float* __restrict__ outT, float* __restrict__ outC)
{
    extern __shared__ __align__(16) char smem[];
    unsigned short* W1A = (unsigned short*)smem;
    unsigned short* TCM = (unsigned short*)(smem + 2304);
    float*          TF  = (float*)(smem + 22784);
    unsigned short* W2A = (unsigned short*)(smem + 39424);
    int*            MK  = (int*)(smem + 44544);
    float*          SMX = (float*)(smem + 44800);
    float*          SSM = SMX + 64;
    unsigned short* TQ  = (unsigned short*)(smem + 45312);  // [16][264]

    const int bt = blockIdx.x, tid = threadIdx.x;
    const int lane = tid & 63, w = tid >> 6;
    const int l16 = lane & 15, l4 = lane >> 4;
    const unsigned short* eR = emb + (size_t)bt * 32768;
    const unsigned short* eC = eR + 16384;

    if (tid < 64) MK[tid] = amask[(size_t)bt * 64 + tid];
#pragma unroll
    for (int i = 0; i < 16; ++i) {
        int idx = tid + i * 256;
        int row = idx >> 8, col = idx & 255;
        TQ[row * 264 + col] = f2bf(tq[idx]);
    }
    __syncthreads();

    float sv[4]; int msk;
    {
        f32x4 acc = {};
#pragma unroll
        for (int kk = 0; kk < 8; ++kk) {
            int ko = kk*32 + l4*8;
            bf16x8 a = ldsb8(TQ + l16 * 264 + ko);
            bf16x8 b = ldsb8(eR + (w*16 + l16) * 256 + ko);
            acc = __builtin_amdgcn_mfma_f32_16x16x32_bf16(a, b, acc, 0, 0, 0);
        }
        msk = MK[w*16 + l16];
#pragma unroll
        for (int i = 0; i < 4; ++i) sv[i] = msk ? acc[i] * 0.0625f : -3.0e38f;
        float mx[4];
#pragma unroll
        for (int i = 0; i < 4; ++i) {
            float m = sv[i];
#pragma unroll
            for (int off = 1; off < 16; off <<= 1) m = fmaxf(m, __shfl_xor(m, off, 16));
            mx[i] = m;
        }
        if (l16 == 0) {
#pragma unroll
            for (int i = 0; i < 4; ++i) SMX[(l4*4 + i) * 4 + w] = mx[i];
        }
    }
    __syncthreads();
    float ev[4];
    {
#pragma unroll
        for (int i = 0; i < 4; ++i) {
            int q = l4*4 + i;
            float g = fmaxf(fmaxf(SMX[q*4+0], SMX[q*4+1]), fmaxf(SMX[q*4+2], SMX[q*4+3]));
            ev[i] = msk ? __expf(sv[i] - g) : 0.f;
            float s = ev[i];
#pragma unroll
            for (int off = 1; off < 16; off <<= 1) s += __shfl_xor(s, off, 16);
            if (l16 == 0) SSM[q*4 + w] = s;
        }
    }
    __syncthreads();
    {
#pragma unroll
        for (int i = 0; i < 4; ++i) {
            int q = l4*4 + i;
            float tot = SSM[q*4+0] + SSM[q*4+1] + SSM[q*4+2] + SSM[q*4+3];
            float w1 = ev[i] * (1.0f / fmaxf(tot, 1e-8f));
            W1A[q * 72 + w*16 + l16] = f2bf(w1);
        }
    }
    __syncthreads();

    {
        bf16x8 bW[2];
#pragma unroll
        for (int kk = 0; kk < 2; ++kk) bW[kk] = ldsb8(W1A + l16 * 72 + kk*32 + l4*8);
#pragma unroll
        for (int p = 0; p < 4; ++p) {
            int dt = w + p * 4;
            f32x4 acc = {};
#pragma unroll
            for (int kk = 0; kk < 2; ++kk) {
                bf16x8 a = ldsb8(eC + (dt*16 + l16) * 64 + kk*32 + l4*8);
                acc = __builtin_amdgcn_mfma_f32_16x16x32_bf16(a, bW[kk], acc, 0, 0, 0);
            }
#pragma unroll
            for (int i = 0; i < 4; ++i) {
                int d = dt*16 + l4*4 + i;
                TCM[d * 40 + l16]      = f2bf(acc[i]);
                TCM[d * 40 + 16 + l16] = 0;
                TF[l16 * 260 + d]      = acc[i];
            }
        }
    }
    __syncthreads();

    {
        float* oT = outT + (size_t)bt * 4096;
#pragma unroll
        for (int it = 0; it < 16; ++it) {
            int idx = tid + it * 256;
            oT[idx] = TF[(idx >> 8) * 260 + (idx & 255)];
        }
    }

    {
        f32x4 acc = {};
#pragma unroll
        for (int kk = 0; kk < 8; ++kk) {
            int ko = kk*32 + l4*8;
            bf16x8 a = ldsb8(eR + (w*16 + l16) * 256 + ko);
            const float* tp = TF + l16 * 260 + ko;
            f32x4 t0 = *(const f32x4*)tp;
            f32x4 t1 = *(const f32x4*)(tp + 4);
            bf16x8 b;
            b[0]=(__bf16)t0.x; b[1]=(__bf16)t0.y; b[2]=(__bf16)t0.z; b[3]=(__bf16)t0.w;
            b[4]=(__bf16)t1.x; b[5]=(__bf16)t1.y; b[6]=(__bf16)t1.z; b[7]=(__bf16)t1.w;
            acc = __builtin_amdgcn_mfma_f32_16x16x32_bf16(a, b, acc, 0, 0, 0);
        }
#pragma unroll
        for (int i = 0; i < 4; ++i) {
            float s = acc[i] * 0.0625f;
            float m = s;
#pragma unroll
            for (int off = 1; off < 16; off <<= 1) m = fmaxf(m, __shfl_xor(m, off, 16));
            float e = __expf(s - m);
            float su = e;
#pragma unroll
            for (int off = 1; off < 16; off <<= 1) su += __shfl_xor(su, off, 16);
            float w2 = e / su;
            int ag = w*16 + l4*4 + i;
            W2A[ag * 40 + l16]      = f2bf(w2);
            W2A[ag * 40 + 16 + l16] = 0;
        }
    }
    __syncthreads();

    {
        float* oC = outC + (size_t)bt * 16384;
        bf16x8 a = ldsb8(W2A + (w*16 + l16) * 40 + l4*8);
#pragma unroll
        for (int dt = 0; dt < 16; ++dt) {
            bf16x8 b = ldsb8(TCM + (dt*16 + l16) * 40 + l4*8);
            f32x4 acc = {};
            acc = __builtin_amdgcn_mfma_f32_16x16x32_bf16(a, b, acc, 0, 0, 0);
#pragma unroll
            for (int i = 0; i < 4; ++i) {
                int ag = w*16 + l4*4 + i;
                float m = (float)MK[ag];
                oC[ag * 256 + dt*16 + l16] = acc[i] * m;
            }
        }
    }
}

extern "C" void kernel_launch(void* const* d_in, const int* in_sizes, int n_in,
                              void* d_out, int out_size, void* d_ws, size_t ws_size,
                              hipStream_t stream) {
    (void)in_sizes; (void)n_in; (void)out_size; (void)ws_size;
    const float* obs   = (const float*)d_in[0];
    const int*   amask = (const int*)d_in[1];
    const float* W1    = (const float*)d_in[2];
    const float* b1    = (const float*)d_in[3];
    const float* W2    = (const float*)d_in[4];
    const float* b2    = (const float*)d_in[5];
    const float* W3    = (const float*)d_in[6];
    const float* b3    = (const float*)d_in[7];
    const float* tq    = (const float*)d_in[8];

    unsigned short* wt1 = (unsigned short*)d_ws;       // 65536 elems (frag-packed)
    unsigned short* wt2 = wt1 + 65536;                 // 262144 elems
    unsigned short* wt3 = wt2 + 262144;                // 131072 elems

    float* outT = (float*)d_out;
    float* outC = outT + (size_t)BT_TOTAL * 16 * 256;
    unsigned short* embWS = (unsigned short*)outC;     // emb staged in outC region

    prep_pack<<<896, 512, 0, stream>>>(W1, W2, W3, wt1, wt2, wt3);
    mlp_kernel<<<BT_TOTAL, 512, K1_LDS, stream>>>(
        obs, wt1, b1, wt2, b2, wt3, b3, embWS);
    attn_kernel<<<BT_TOTAL, 256, K2_LDS, stream>>>(
        amask, tq, embWS, outT, outC);
}

// Round 18
// 100.744 us; speedup vs baseline: 1.6018x; 1.0220x over previous
//
#include <hip/hip_runtime.h>
#include <hip/hip_bf16.h>

#define BT_TOTAL 1024

typedef __bf16 bf16x8 __attribute__((ext_vector_type(8)));
typedef float  f32x4  __attribute__((ext_vector_type(4)));
typedef int    i32x4  __attribute__((ext_vector_type(4)));
typedef short  s16x4  __attribute__((ext_vector_type(4)));

__device__ inline unsigned short f2bf(float f) {
    unsigned int u = __builtin_bit_cast(unsigned int, f);
    u = (u + 0x7FFFu + ((u >> 16) & 1u)) >> 16;
    return (unsigned short)u;
}

__device__ inline bf16x8 ldsb8(const unsigned short* p) {
    i32x4 t = *(const i32x4*)p;
    return __builtin_bit_cast(bf16x8, t);
}

#define SB0() __builtin_amdgcn_sched_barrier(0)

// Counter separation (r15-proven): B on vmcnt (asm gloads), A on lgkmcnt —
// the ONLY ops on each counter inside K-loops (biases/epilogues behind
// __syncthreads). Counted waits exact. SB0 after each wait = rule-18 fence.
#define WAITV4() do { \
    asm volatile("s_waitcnt vmcnt(4)" ::: "memory"); SB0(); } while (0)
#define WAITV2() do { \
    asm volatile("s_waitcnt vmcnt(2)" ::: "memory"); SB0(); } while (0)
#define WAITV0() do { \
    asm volatile("s_waitcnt vmcnt(0)" ::: "memory"); SB0(); } while (0)

// global -> VGPR, saddr form; asm volatile = cannot be sunk/folded (r8/r9 fix).
#define GLOAD4(d, vo, sb, IMM) \
    asm volatile("global_load_dwordx4 %0, %1, %2 offset:" IMM \
                 : "=v"(d) : "v"(vo), "s"(sb) : "memory")

// ---------------- prep: fragment-direct pack (r9/r15-verified layout) ----------------
__global__ __launch_bounds__(512) void prep_pack(
    const float* __restrict__ W1, const float* __restrict__ W2,
    const float* __restrict__ W3,
    unsigned short* __restrict__ wt1, unsigned short* __restrict__ wt2,
    unsigned short* __restrict__ wt3)
{
    int p = blockIdx.x * 512 + threadIdx.x;      // 0 .. 458751
    const float* src; unsigned short* dst; int N_, Wc;
    if (p < 65536)       { src = W1; dst = wt1; N_ = 512; Wc = 64; }
    else if (p < 327680) { p -= 65536;  src = W2; dst = wt2; N_ = 512; Wc = 64; }
    else                 { p -= 327680; src = W3; dst = wt3; N_ = 256; Wc = 32; }
    int k = p / N_, n = p % N_;
    int t = k >> 5, kk = k & 31, l4 = kk >> 3, j = kk & 7;
    int wv = n / Wc, nc = n % Wc, nt = nc >> 4, l16 = nc & 15;
    int off = t * (N_ * 32) + wv * (Wc * 32) + nt * 512 + (l4 * 16 + l16) * 8 + j;
    dst[off] = f2bf(src[(size_t)k * N_ + n]);
}

// ======================= K1: fused MLP — B in registers, A via LDS =======================
// LDS: H [64][520]us = 66560 -> 2 blocks/CU. obs staged into H cols 0..127 for L1.
// EMB overlay [64][264]us @0 post-L3.
#define K1_LDS 66560

__global__ __launch_bounds__(512, 4) void mlp_kernel(
    const float* __restrict__ obs,
    const unsigned short* __restrict__ C1, const float* __restrict__ b1,
    const unsigned short* __restrict__ C2, const float* __restrict__ b2,
    const unsigned short* __restrict__ C3, const float* __restrict__ b3,
    unsigned short* __restrict__ embOut)   // per bt: RM [64][256] then CM [256][64]
{
    extern __shared__ __align__(16) char smem[];
    unsigned short* H   = (unsigned short*)smem;   // [64][520]
    unsigned short* EMB = (unsigned short*)smem;   // [64][264] (post-L3 overlay)

    const int bt = blockIdx.x, tid = threadIdx.x;
    const int lane = tid & 63, wv = tid >> 6;   // 8 waves
    const int l16 = lane & 15, l4 = lane >> 4;

    const int voff  = wv * 4096 + lane * 16;    // L1/L2 slice
    const int voff3 = wv * 2048 + lane * 16;    // L3 slice

    i32x4 breg[2][4];

    // ---- prologue: issue B1(0); stage obs -> H cols 0..127 (bf16) ----
    GLOAD4(breg[0][0], voff, C1, "0");
    GLOAD4(breg[0][1], voff, C1, "1024");
    GLOAD4(breg[0][2], voff, C1, "2048");
    GLOAD4(breg[0][3], voff, C1, "3072");
    {
        const f32x4* src = (const f32x4*)(obs + (size_t)bt * 8192);
#pragma unroll
        for (int i = 0; i < 4; ++i) {
            int idx = tid + i * 512;            // 0..2047
            f32x4 v = src[idx];
            int row = idx >> 5, c4 = idx & 31;
            s16x4 s;
            s[0] = (short)f2bf(v.x); s[1] = (short)f2bf(v.y);
            s[2] = (short)f2bf(v.z); s[3] = (short)f2bf(v.w);
            *(s16x4*)(H + row * 520 + c4 * 4) = s;
        }
    }
    __syncthreads();   // drains obs loads + B1(0); H cols 0..127 = obs bf16

    // ---- L1: 4 steps; A from H cols 0..127 ----
    // mfma(b, a, acc) computes C^T: acc[i] -> (col n = l4*4+i, row m = l16)
    f32x4 acc1[4][4] = {};
#pragma unroll
    for (int t = 0; t < 4; ++t) {
        if (t < 3) {
            const unsigned short* sb = C1 + (size_t)(t + 1) * 16384;
            GLOAD4(breg[(t + 1) & 1][0], voff, sb, "0");
            GLOAD4(breg[(t + 1) & 1][1], voff, sb, "1024");
            GLOAD4(breg[(t + 1) & 1][2], voff, sb, "2048");
            GLOAD4(breg[(t + 1) & 1][3], voff, sb, "3072");
            WAITV4();
        } else WAITV0();
        bf16x8 afr[4];
#pragma unroll
        for (int mt = 0; mt < 4; ++mt)
            afr[mt] = ldsb8(H + (mt * 16 + l16) * 520 + t * 32 + l4 * 8);
        __builtin_amdgcn_s_setprio(1);
#pragma unroll
        for (int nt = 0; nt < 4; ++nt) {
            bf16x8 bq = __builtin_bit_cast(bf16x8, breg[t & 1][nt]);
#pragma unroll
            for (int mt = 0; mt < 4; ++mt)
                acc1[mt][nt] = __builtin_amdgcn_mfma_f32_16x16x32_bf16(bq, afr[mt], acc1[mt][nt], 0, 0, 0);
        }
        __builtin_amdgcn_s_setprio(0);
    }
    __syncthreads();   // ALL waves' obs reads done before H overwrite
    // epilogue: H = relu(acc1^T + b1); issue B2(0) before the publishing sync
    {
        f32x4 bv[4];
#pragma unroll
        for (int nt = 0; nt < 4; ++nt)
            bv[nt] = *(const f32x4*)(b1 + wv * 64 + nt * 16 + l4 * 4);
#pragma unroll
        for (int mt = 0; mt < 4; ++mt) {
            int row = mt * 16 + l16;
#pragma unroll
            for (int nt = 0; nt < 4; ++nt) {
                f32x4 v = acc1[mt][nt] + bv[nt];
                s16x4 s;
#pragma unroll
                for (int i = 0; i < 4; ++i) s[i] = (short)f2bf(fmaxf(v[i], 0.f));
                *(s16x4*)(H + row * 520 + wv * 64 + nt * 16 + l4 * 4) = s;
            }
        }
    }
    GLOAD4(breg[0][0], voff, C2, "0");
    GLOAD4(breg[0][1], voff, C2, "1024");
    GLOAD4(breg[0][2], voff, C2, "2048");
    GLOAD4(breg[0][3], voff, C2, "3072");
    __syncthreads();   // H1 visible; B2(0) drained

    // ---- L2: 16 steps ----
    f32x4 acc2[4][4] = {};
#pragma unroll
    for (int t = 0; t < 16; ++t) {
        if (t < 15) {
            const unsigned short* sb = C2 + (size_t)(t + 1) * 16384;
            GLOAD4(breg[(t + 1) & 1][0], voff, sb, "0");
            GLOAD4(breg[(t + 1) & 1][1], voff, sb, "1024");
            GLOAD4(breg[(t + 1) & 1][2], voff, sb, "2048");
            GLOAD4(breg[(t + 1) & 1][3], voff, sb, "3072");
            WAITV4();
        } else WAITV0();
        bf16x8 afr[4];
#pragma unroll
        for (int mt = 0; mt < 4; ++mt)
            afr[mt] = ldsb8(H + (mt * 16 + l16) * 520 + t * 32 + l4 * 8);
        __builtin_amdgcn_s_setprio(1);
#pragma unroll
        for (int nt = 0; nt < 4; ++nt) {
            bf16x8 bq = __builtin_bit_cast(bf16x8, breg[t & 1][nt]);
#pragma unroll
            for (int mt = 0; mt < 4; ++mt)
                acc2[mt][nt] = __builtin_amdgcn_mfma_f32_16x16x32_bf16(bq, afr[mt], acc2[mt][nt], 0, 0, 0);
        }
        __builtin_amdgcn_s_setprio(0);
    }
    __syncthreads();   // all H1 reads done before overwrite
    {
        f32x4 bv[4];
#pragma unroll
        for (int nt = 0; nt < 4; ++nt)
            bv[nt] = *(const f32x4*)(b2 + wv * 64 + nt * 16 + l4 * 4);
#pragma unroll
        for (int mt = 0; mt < 4; ++mt) {
            int row = mt * 16 + l16;
#pragma unroll
            for (int nt = 0; nt < 4; ++nt) {
                f32x4 v = acc2[mt][nt] + bv[nt];
                s16x4 s;
#pragma unroll
                for (int i = 0; i < 4; ++i) s[i] = (short)f2bf(fmaxf(v[i], 0.f));
                *(s16x4*)(H + row * 520 + wv * 64 + nt * 16 + l4 * 4) = s;
            }
        }
    }
    GLOAD4(breg[0][0], voff3, C3, "0");
    GLOAD4(breg[0][1], voff3, C3, "1024");
    __syncthreads();   // H2 visible; B3(0) drained

    // ---- L3: 16 steps (K=512), N=256 ----
    f32x4 acc3[4][2] = {};
#pragma unroll
    for (int t = 0; t < 16; ++t) {
        if (t < 15) {
            const unsigned short* sb = C3 + (size_t)(t + 1) * 8192;
            GLOAD4(breg[(t + 1) & 1][0], voff3, sb, "0");
            GLOAD4(breg[(t + 1) & 1][1], voff3, sb, "1024");
            WAITV2();
        } else WAITV0();
        bf16x8 afr[4];
#pragma unroll
        for (int mt = 0; mt < 4; ++mt)
            afr[mt] = ldsb8(H + (mt * 16 + l16) * 520 + t * 32 + l4 * 8);
        __builtin_amdgcn_s_setprio(1);
#pragma unroll
        for (int nt = 0; nt < 2; ++nt) {
            bf16x8 bq = __builtin_bit_cast(bf16x8, breg[t & 1][nt]);
#pragma unroll
            for (int mt = 0; mt < 4; ++mt)
                acc3[mt][nt] = __builtin_amdgcn_mfma_f32_16x16x32_bf16(bq, afr[mt], acc3[mt][nt], 0, 0, 0);
        }
        __builtin_amdgcn_s_setprio(0);
    }
    __syncthreads();   // all H reads done; EMB overlay writable

    // ---- emb epilogue: bf16 tile in LDS (b64 writes), then global RM + CM ----
    {
        f32x4 bv[2];
#pragma unroll
        for (int nt = 0; nt < 2; ++nt)
            bv[nt] = *(const f32x4*)(b3 + wv * 32 + nt * 16 + l4 * 4);
#pragma unroll
        for (int mt = 0; mt < 4; ++mt) {
            int row = mt * 16 + l16;
#pragma unroll
            for (int nt = 0; nt < 2; ++nt) {
                f32x4 v = acc3[mt][nt] + bv[nt];
                s16x4 s;
#pragma unroll
                for (int i = 0; i < 4; ++i) s[i] = (short)f2bf(v[i]);
                *(s16x4*)(EMB + row * 264 + wv * 32 + nt * 16 + l4 * 4) = s;
            }
        }
    }
    __syncthreads();
    {
        unsigned short* eR = embOut + (size_t)bt * 32768;
        unsigned short* eC = eR + 16384;
        // RM: [64][256] = 2048 x 16B groups (coalesced)
#pragma unroll
        for (int u = 0; u < 4; ++u) {
            int uu = tid + u * 512;                 // 0..2047
            int row = uu >> 5, c8 = (uu & 31) * 8;
            i32x4 v = *(const i32x4*)(EMB + row * 264 + c8);
            *(i32x4*)(eR + uu * 8) = v;             // eR[row*256 + c8]
        }
        // CM: lane <-> column-consecutive (2-way LDS reads, free)
#pragma unroll
        for (int u = 0; u < 4; ++u) {
            int v = tid + u * 512;                  // 0..2047
            int col = v & 255, rg = v >> 8;
            i32x4 w;
#pragma unroll
            for (int j = 0; j < 4; ++j) {
                unsigned int a = EMB[(rg * 8 + 2 * j) * 264 + col];
                unsigned int b = EMB[(rg * 8 + 2 * j + 1) * 264 + col];
                w[j] = (int)(a | (b << 16));
            }
            *(i32x4*)(eC + col * 64 + rg * 8) = w;  // eC[col*64 + rg*8]
        }
    }
}

// ======================= K2: attention (unchanged, verified) =======================
// LDS: W1A [16][72]us @0 (2304) ; TCM [256][40]us @2304 (20480) ;
//      TF [16][260]f32 @22784 (16640) ; W2A [64][40]us @39424 (5120) ;
//      MK [64]i32 @44544 (256) ; SMX/SSM @44800 (512) ; TQ [16][264]us @45312 (8448)
#define K2_LDS 53760

__global__ void attn_kernel(const int* __restrict__ amask,
                            const float* __restrict__ tq,
                            const unsigned short* __restrict__ emb,
                            float* __restrict__ outT, float* __restrict__ outC)
{
    extern __shared__ __align__(16) char smem[];
    unsigned short* W1A = (unsigned short*)smem;
    unsigned short* TCM = (unsigned short*)(smem + 2304);
    float*          TF  = (float*)(smem + 22784);
    unsigned short* W2A = (unsigned short*)(smem + 39424);
    int*            MK  = (int*)(smem + 44544);
    float*          SMX = (float*)(smem + 44800);
    float*          SSM = SMX + 64;
    unsigned short* TQ  = (unsigned short*)(smem + 45312);  // [16][264]

    const int bt = blockIdx.x, tid = threadIdx.x;
    const int lane = tid & 63, w = tid >> 6;
    const int l16 = lane & 15, l4 = lane >> 4;
    const unsigned short* eR = emb + (size_t)bt * 32768;
    const unsigned short* eC = eR + 16384;

    if (tid < 64) MK[tid] = amask[(size_t)bt * 64 + tid];
#pragma unroll
    for (int i = 0; i < 16; ++i) {
        int idx = tid + i * 256;
        int row = idx >> 8, col = idx & 255;
        TQ[row * 264 + col] = f2bf(tq[idx]);
    }
    __syncthreads();

    float sv[4]; int msk;
    {
        f32x4 acc = {};
#pragma unroll
        for (int kk = 0; kk < 8; ++kk) {
            int ko = kk*32 + l4*8;
            bf16x8 a = ldsb8(TQ + l16 * 264 + ko);
            bf16x8 b = ldsb8(eR + (w*16 + l16) * 256 + ko);
            acc = __builtin_amdgcn_mfma_f32_16x16x32_bf16(a, b, acc, 0, 0, 0);
        }
        msk = MK[w*16 + l16];
#pragma unroll
        for (int i = 0; i < 4; ++i) sv[i] = msk ? acc[i] * 0.0625f : -3.0e38f;
        float mx[4];
#pragma unroll
        for (int i = 0; i < 4; ++i) {
            float m = sv[i];
#pragma unroll
            for (int off = 1; off < 16; off <<= 1) m = fmaxf(m, __shfl_xor(m, off, 16));
            mx[i] = m;
        }
        if (l16 == 0) {
#pragma unroll
            for (int i = 0; i < 4; ++i) SMX[(l4*4 + i) * 4 + w] = mx[i];
        }
    }
    __syncthreads();
    float ev[4];
    {
#pragma unroll
        for (int i = 0; i < 4; ++i) {
            int q = l4*4 + i;
            float g = fmaxf(fmaxf(SMX[q*4+0], SMX[q*4+1]), fmaxf(SMX[q*4+2], SMX[q*4+3]));
            ev[i] = msk ? __expf(sv[i] - g) : 0.f;
            float s = ev[i];
#pragma unroll
            for (int off = 1; off < 16; off <<= 1) s += __shfl_xor(s, off, 16);
            if (l16 == 0) SSM[q*4 + w] = s;
        }
    }
    __syncthreads();
    {
#pragma unroll
        for (int i = 0; i < 4; ++i) {
            int q = l4*4 + i;
            float tot = SSM[q*4+0] + SSM[q*4+1] + SSM[q*4+2] + SSM[q*4+3];
            float w1 = ev[i] * (1.0f / fmaxf(tot, 1e-8f));
            W1A[q * 72 + w*16 + l16] = f2bf(w1);
        }
    }
    __syncthreads();

    {
        bf16x8 bW[2];
#pragma unroll
        for (int kk = 0; kk < 2; ++kk) bW[kk] = ldsb8(W1A + l16 * 72 + kk*32 + l4*8);
#pragma unroll
        for (int p = 0; p < 4; ++p) {
            int dt = w + p * 4;
            f32x4 acc = {};
#pragma unroll
            for (int kk = 0; kk < 2; ++kk) {
                bf16x8 a = ldsb8(eC + (dt*16 + l16) * 64 + kk*32 + l4*8);
                acc = __builtin_amdgcn_mfma_f32_16x16x32_bf16(a, bW[kk], acc, 0, 0, 0);
            }
#pragma unroll
            for (int i = 0; i < 4; ++i) {
                int d = dt*16 + l4*4 + i;
                TCM[d * 40 + l16]      = f2bf(acc[i]);
                TCM[d * 40 + 16 + l16] = 0;
                TF[l16 * 260 + d]      = acc[i];
            }
        }
    }
    __syncthreads();

    {
        float* oT = outT + (size_t)bt * 4096;
#pragma unroll
        for (int it = 0; it < 16; ++it) {
            int idx = tid + it * 256;
            oT[idx] = TF[(idx >> 8) * 260 + (idx & 255)];
        }
    }

    {
        f32x4 acc = {};
#pragma unroll
        for (int kk = 0; kk < 8; ++kk) {
            int ko = kk*32 + l4*8;
            bf16x8 a = ldsb8(eR + (w*16 + l16) * 256 + ko);
            const float* tp = TF + l16 * 260 + ko;
            f32x4 t0 = *(const f32x4*)tp;
            f32x4 t1 = *(const f32x4*)(tp + 4);
            bf16x8 b;
            b[0]=(__bf16)t0.x; b[1]=(__bf16)t0.y; b[2]=(__bf16)t0.z; b[3]=(__bf16)t0.w;
            b[4]=(__bf16)t1.x; b[5]=(__bf16)t1.y; b[6]=(__bf16)t1.z; b[7]=(__bf16)t1.w;
            acc = __builtin_amdgcn_mfma_f32_16x16x32_bf16(a, b, acc, 0, 0, 0);
        }
#pragma unroll
        for (int i = 0; i < 4; ++i) {
            float s = acc[i] * 0.0625f;
            float m = s;
#pragma unroll
            for (int off = 1; off < 16; off <<= 1) m = fmaxf(m, __shfl_xor(m, off, 16));
            float e = __expf(s - m);
            float su = e;
#pragma unroll
            for (int off = 1; off < 16; off <<= 1) su += __shfl_xor(su, off, 16);
            float w2 = e / su;
            int ag = w*16 + l4*4 + i;
            W2A[ag * 40 + l16]      = f2bf(w2);
            W2A[ag * 40 + 16 + l16] = 0;
        }
    }
    __syncthreads();

    {
        float* oC = outC + (size_t)bt * 16384;
        bf16x8 a = ldsb8(W2A + (w*16 + l16) * 40 + l4*8);
#pragma unroll
        for (int dt = 0; dt < 16; ++dt) {
            bf16x8 b = ldsb8(TCM + (dt*16 + l16) * 40 + l4*8);
            f32x4 acc = {};
            acc = __builtin_amdgcn_mfma_f32_16x16x32_bf16(a, b, acc, 0, 0, 0);
#pragma unroll
            for (int i = 0; i < 4; ++i) {
                int ag = w*16 + l4*4 + i;
                float m = (float)MK[ag];
                oC[ag * 256 + dt*16 + l16] = acc[i] * m;
            }
        }
    }
}

extern "C" void kernel_launch(void* const* d_in, const int* in_sizes, int n_in,
                              void* d_out, int out_size, void* d_ws, size_t ws_size,
                              hipStream_t stream) {
    (void)in_sizes; (void)n_in; (void)out_size; (void)ws_size;
    const float* obs   = (const float*)d_in[0];
    const int*   amask = (const int*)d_in[1];
    const float* W1    = (const float*)d_in[2];
    const float* b1    = (const float*)d_in[3];
    const float* W2    = (const float*)d_in[4];
    const float* b2    = (const float*)d_in[5];
    const float* W3    = (const float*)d_in[6];
    const float* b3    = (const float*)d_in[7];
    const float* tq    = (const float*)d_in[8];

    unsigned short* wt1 = (unsigned short*)d_ws;       // 65536 elems (frag-packed)
    unsigned short* wt2 = wt1 + 65536;                 // 262144 elems
    unsigned short* wt3 = wt2 + 262144;                // 131072 elems

    float* outT = (float*)d_out;
    float* outC = outT + (size_t)BT_TOTAL * 16 * 256;
    unsigned short* embWS = (unsigned short*)outC;     // emb staged in outC region

    prep_pack<<<896, 512, 0, stream>>>(W1, W2, W3, wt1, wt2, wt3);
    mlp_kernel<<<BT_TOTAL, 512, K1_LDS, stream>>>(
        obs, wt1, b1, wt2, b2, wt3, b3, embWS);
    attn_kernel<<<BT_TOTAL, 256, K2_LDS, stream>>>(
        amask, tq, embWS, outT, outC);
}